// Round 3
// baseline (781.929 us; speedup 1.0000x reference)
//
#include <hip/hip_runtime.h>
#include <hip/hip_bf16.h>
#include <math.h>

#define D_MODEL 2816
#define DM4 704          // D_MODEL/4
#define D_DENSE 2112
#define N_EXPERTS 128
#define D_FFN 704
#define DF4 176          // D_FFN/4
#define TOPK 8
#define H 16
#define DH 256
#define NKV 8
#define MAX_CTX 4096
#define EPS 1e-6f

__device__ __forceinline__ float wsum(float v){
  #pragma unroll
  for(int o=32;o>0;o>>=1) v += __shfl_down(v, o, 64);
  return v;
}
__device__ __forceinline__ float wmax(float v){
  #pragma unroll
  for(int o=32;o>0;o>>=1) v = fmaxf(v, __shfl_down(v, o, 64));
  return v;
}
__device__ __forceinline__ float wsum_all(float v){
  #pragma unroll
  for(int o=32;o>0;o>>=1) v += __shfl_xor(v, o, 64);
  return v;
}
__device__ __forceinline__ float wmax_all(float v){
  #pragma unroll
  for(int o=32;o>0;o>>=1) v = fmaxf(v, __shfl_xor(v, o, 64));
  return v;
}
__device__ __forceinline__ int wmin_all_i(int v){
  #pragma unroll
  for(int o=32;o>0;o>>=1) v = min(v, __shfl_xor(v, o, 64));
  return v;
}
__device__ __forceinline__ float block_sum(float v, float* sm){
  int lane = threadIdx.x & 63, w = threadIdx.x >> 6;
  int nw = blockDim.x >> 6;
  v = wsum(v);
  __syncthreads();
  if (lane == 0) sm[w] = v;
  __syncthreads();
  float t = 0.f;
  for (int i = 0; i < nw; i++) t += sm[i];
  return t;
}
__device__ __forceinline__ float gelu_tanh(float x){
  float x3 = x*x*x;
  return 0.5f*x*(1.f + tanhf(0.7978845608028654f*(x + 0.044715f*x3)));
}
__device__ __forceinline__ float dot4(float4 a, float4 b){
  return fmaf(a.x,b.x, fmaf(a.y,b.y, fmaf(a.z,b.z, a.w*b.w)));
}

// ---------------- K1: rmsnorm(x) + fused q/k/v GEMV; zero counters ----------
__global__ __launch_bounds__(256) void k_qkv(const float* __restrict__ Wq,
    const float* __restrict__ Wk, const float* __restrict__ Wv,
    const float* __restrict__ x, const float* __restrict__ lw,
    float* __restrict__ out, int* __restrict__ cnt){
  __shared__ float sh[D_MODEL];
  __shared__ float sm[8];
  int t = threadIdx.x;
  if (blockIdx.x == 0 && t < 32) cnt[t] = 0;   // replay-safe counter reset
  float xv[11]; float ss = 0.f;
  #pragma unroll
  for (int i=0;i<11;i++){ xv[i] = x[t + 256*i]; ss += xv[i]*xv[i]; }
  ss = block_sum(ss, sm);
  float r = rsqrtf(ss/(float)D_MODEL + EPS);
  #pragma unroll
  for (int i=0;i<11;i++){ int idx=t+256*i; sh[idx] = xv[i]*r*(1.f+lw[idx]); }
  __syncthreads();

  int row = blockIdx.x*4 + (t>>6);
  int lane = t & 63;
  const float* W; int rr;
  if (row < 4096){ W=Wq; rr=row; }
  else if (row < 6144){ W=Wk; rr=row-4096; }
  else { W=Wv; rr=row-6144; }
  const float4* wr = (const float4*)(W + (size_t)rr*D_MODEL);
  const float4* hv = (const float4*)sh;
  float acc=0.f;
  for (int i=lane;i<DM4;i+=64) acc += dot4(wr[i], hv[i]);
  acc = wsum(acc);
  if (lane==0) out[row]=acc;
}

// ---------------- K2: attn partials (blocks 0..255, self-normed) +
//                      KV copy (blocks 256..4351, self-normed) +
//                      per-head last-block combine -> ctx ---------------------
__global__ __launch_bounds__(256) void k_attn_copy(
    const float* __restrict__ kc, const float* __restrict__ vc,
    const float* __restrict__ qkv,
    const float* __restrict__ qw, const float* __restrict__ kw,
    const float* __restrict__ cs, const float* __restrict__ sn,
    const float* __restrict__ wm, const float* __restrict__ mask,
    float* __restrict__ ko, float* __restrict__ vo,
    float* __restrict__ part, float* __restrict__ ctx, int* __restrict__ cnt){
  __shared__ float sm[8];
  int t = threadIdx.x;

  if (blockIdx.x >= 256){
    // ---- KV copy path: one (tensor,head) per block group ----
    __shared__ float nrm[DH];
    int b = blockIdx.x - 256;
    int tensor = b >> 11;            // 0=k, 1=v
    int head = (b >> 8) & 7;
    int blk = b & 255;
    const float* src = qkv + (tensor ? 6144 : 4096) + head*DH;
    float v = src[t];
    float ssq = block_sum(v*v, sm);
    float r = rsqrtf(ssq/(float)DH + EPS);
    float base_ = v*r*(tensor==0 ? (1.f+kw[t]) : 1.f);
    nrm[t] = base_;
    __syncthreads();
    float nv = base_;
    if (tensor == 0){
      float rot = (t<128) ? -nrm[t+128] : nrm[t-128];
      nv = base_*cs[t] + rot*sn[t];
    }
    __syncthreads();
    nrm[t] = nv;
    __syncthreads();
    const float4* cache = (const float4*)(tensor ? vc : kc);
    float4* outp = (float4*)(tensor ? vo : ko);
    const float4* a4 = (const float4*)nrm;
    size_t hb = (size_t)head * (MAX_CTX*(DH/4));
    int lbase = blk*1024;
    #pragma unroll
    for (int q=0;q<4;q++){
      int jl = lbase + q*256 + t;
      int pos = jl >> 6;
      int d4 = jl & 63;
      float m = wm[pos];
      float4 c = cache[hb + jl];
      float4 a = a4[d4];
      c.x = fmaf(a.x,m,c.x); c.y = fmaf(a.y,m,c.y);
      c.z = fmaf(a.z,m,c.z); c.w = fmaf(a.w,m,c.w);
      outp[hb + jl] = c;
    }
    return;
  }

  // ---- attention partial path ----
  __shared__ float qrow[DH], krow[DH], vrow[DH], sc[256], sw[256];
  int head = blockIdx.x >> 4, chunk = blockIdx.x & 15;
  int kvh = head >> 1;                       // rep = H/NKV = 2
  int lane = t & 63, wv = t >> 6;

  {  // q norm + rope
    float v = qkv[head*DH + t];
    float ssq = block_sum(v*v, sm);
    float r = rsqrtf(ssq/(float)DH + EPS);
    float b_ = v*r*(1.f+qw[t]);
    qrow[t]=b_;
    __syncthreads();
    float rot = (t<128) ? -qrow[t+128] : qrow[t-128];
    float nv = b_*cs[t] + rot*sn[t];
    __syncthreads();
    qrow[t]=nv;
  }
  {  // k norm + rope (kvh)
    float v = qkv[4096 + kvh*DH + t];
    float ssq = block_sum(v*v, sm);
    float r = rsqrtf(ssq/(float)DH + EPS);
    float b_ = v*r*(1.f+kw[t]);
    krow[t]=b_;
    __syncthreads();
    float rot = (t<128) ? -krow[t+128] : krow[t-128];
    float nv = b_*cs[t] + rot*sn[t];
    __syncthreads();
    krow[t]=nv;
  }
  {  // v norm (plain)
    float v = qkv[6144 + kvh*DH + t];
    float ssq = block_sum(v*v, sm);
    vrow[t] = v*rsqrtf(ssq/(float)DH + EPS);
  }
  __syncthreads();

  int base = chunk*256;
  float mk_t = mask[base + t];
  float live = block_sum((mk_t > -1e8f) ? 1.f : 0.f, sm);
  float* p = part + (size_t)(head*16+chunk)*258;
  if (live != 0.f){
    float4 q  = ((const float4*)qrow)[lane];
    float4 kp = ((const float4*)krow)[lane];
    float vp  = vrow[t];
    const float* K = kc + (size_t)kvh*MAX_CTX*DH;
    const float* V = vc + (size_t)kvh*MAX_CTX*DH;
    for (int i=0;i<64;i++){
      int pp = wv*64 + i;
      int pos = base + pp;
      float mk = mask[pos];
      float s = -3.0e38f;
      if (mk > -1e8f){                          // wave-uniform
        float m = wm[pos];
        float4 kv = ((const float4*)(K + (size_t)pos*DH))[lane];
        kv.x = fmaf(kp.x, m, kv.x); kv.y = fmaf(kp.y, m, kv.y);
        kv.z = fmaf(kp.z, m, kv.z); kv.w = fmaf(kp.w, m, kv.w);
        float d = wsum(dot4(q, kv));
        s = d + mk;
      }
      if (lane==0) sc[pp] = s;
    }
    __syncthreads();
    float sv = sc[t];
    float mx = wmax(sv);
    __syncthreads();
    if (lane==0) sm[wv]=mx;
    __syncthreads();
    mx = fmaxf(fmaxf(sm[0],sm[1]),fmaxf(sm[2],sm[3]));
    float w = (sv > -1e30f) ? __expf(sv - mx) : 0.f;
    sw[t] = w;
    float ssum = block_sum(w, sm);
    float acc = 0.f;
    for (int i=0;i<256;i++){
      float wi = sw[i];
      if (wi != 0.f){
        float v = fmaf(vp, wm[base+i], V[(size_t)(base+i)*DH + t]);
        acc = fmaf(wi, v, acc);
      }
    }
    if (t==0){ p[0]=mx; p[1]=ssum; }
    p[2+t]=acc;
  } else {
    if (t == 0){ p[0] = -3.0e38f; p[1] = 0.f; }
  }

  // ---- per-head last-block combine ----
  __threadfence();
  __syncthreads();
  __shared__ int lastf;
  if (t==0) lastf = (atomicAdd(&cnt[head],1) == 15);
  __syncthreads();
  if (lastf){
    __threadfence();
    float M = -3.0e38f;
    for (int c=0;c<16;c++) M = fmaxf(M, part[(size_t)(head*16+c)*258]);
    float tot = 0.f, acc = 0.f;
    for (int c=0;c<16;c++){
      const float* pc = part + (size_t)(head*16+c)*258;
      float mc=pc[0], scv=pc[1];
      if (scv > 0.f){
        float f = __expf(mc - M);
        tot = fmaf(scv, f, tot);
        acc = fmaf(f, pc[2+t], acc);
      }
    }
    ctx[head*DH + t] = acc / tot;
  }
}

// ---------------- K3: Wo GEMV + last-block postattn -------------------------
__global__ __launch_bounds__(256) void k_wo_post(const float* __restrict__ Wo,
    const float* __restrict__ ctxv, const float* __restrict__ x,
    const float* __restrict__ wpost, const float* __restrict__ wpre,
    const float* __restrict__ rscale, const float* __restrict__ wpre2,
    float* __restrict__ a, float* __restrict__ x1, float* __restrict__ pre,
    float* __restrict__ hr, float* __restrict__ pre2, int* __restrict__ cnt){
  __shared__ float sm[8];
  int t = threadIdx.x, lane = t & 63, wv = t >> 6;
  int row = blockIdx.x*4 + wv;
  const float4* wr = (const float4*)(Wo + (size_t)row*4096);
  const float4* xv = (const float4*)ctxv;
  float acc = 0.f;
  for (int i=lane;i<1024;i+=64) acc += dot4(wr[i], xv[i]);
  acc = wsum(acc);
  if (lane==0) a[row]=acc;

  __threadfence();
  __syncthreads();
  __shared__ int lastf;
  if (t==0) lastf = (atomicAdd(&cnt[16],1) == 703);
  __syncthreads();
  if (lastf){
    __threadfence();
    float av[11]; float ss=0.f;
    #pragma unroll
    for (int i=0;i<11;i++){ av[i]=a[t+256*i]; ss += av[i]*av[i]; }
    ss = block_sum(ss, sm);
    float ra = rsqrtf(ss/(float)D_MODEL + EPS);
    float xvv[11]; float ss2=0.f;
    #pragma unroll
    for (int i=0;i<11;i++){
      int idx=t+256*i;
      xvv[i] = x[idx] + av[i]*ra*(1.f+wpost[idx]);
      ss2 += xvv[i]*xvv[i];
    }
    ss2 = block_sum(ss2, sm);
    float r1 = rsqrtf(ss2/(float)D_MODEL + EPS);
    const float invsq = rsqrtf((float)D_MODEL);
    #pragma unroll
    for (int i=0;i<11;i++){
      int idx=t+256*i;
      float n = xvv[i]*r1;
      x1[idx]=xvv[i];
      pre[idx]=n*(1.f+wpre[idx]);
      hr[idx]=n*rscale[idx]*invsq;
      pre2[idx]=n*(1.f+wpre2[idx]);
    }
  }
}

// ---------------- K4: dense g/u + router logits + last-router-block top-8 ----
__global__ __launch_bounds__(256) void k_dense_router(const float* __restrict__ Wg,
    const float* __restrict__ Wu, const float* __restrict__ pre,
    const float* __restrict__ Wp, const float* __restrict__ hr,
    const float* __restrict__ pes,
    float* __restrict__ act, float* __restrict__ lg,
    float* __restrict__ selw, int* __restrict__ seli, int* __restrict__ cnt){
  int t = threadIdx.x, lane = t & 63, wv = t >> 6;
  if (blockIdx.x < 528){
    int row = blockIdx.x*4 + wv;
    const float4* g4 = (const float4*)(Wg + (size_t)row*D_MODEL);
    const float4* u4 = (const float4*)(Wu + (size_t)row*D_MODEL);
    const float4* xv = (const float4*)pre;
    float ag=0.f, au=0.f;
    for (int i=lane;i<DM4;i+=64){
      float4 b = xv[i];
      ag += dot4(g4[i], b);
      au += dot4(u4[i], b);
    }
    ag = wsum(ag); au = wsum(au);
    if (lane==0) act[row] = gelu_tanh(ag)*au;
    return;
  }
  // router logits
  int row = (blockIdx.x-528)*4 + wv;       // 0..127
  const float4* wr = (const float4*)(Wp + (size_t)row*D_MODEL);
  const float4* xv = (const float4*)hr;
  float acc = 0.f;
  for (int i=lane;i<DM4;i+=64) acc += dot4(wr[i], xv[i]);
  acc = wsum(acc);
  if (lane==0) lg[row]=acc;

  __threadfence();
  __syncthreads();
  __shared__ int lastf;
  if (t==0) lastf = (atomicAdd(&cnt[17],1) == 31);
  __syncthreads();
  if (lastf){
    __threadfence();
    if (t < 64){
      int ln = t;
      float l0 = lg[ln], l1 = lg[ln+64];
      float m = wmax_all(fmaxf(l0,l1));
      float e0 = __expf(l0-m), e1 = __expf(l1-m);
      float s = wsum_all(e0+e1);
      float p0 = e0/s, p1 = e1/s;
      float vals[8]; int idxs[8]; float tw=0.f;
      #pragma unroll
      for (int ts=0;ts<8;ts++){
        float mx = wmax_all(fmaxf(p0,p1));
        int cand = 0x7fffffff;
        if (p0 == mx) cand = ln;
        else if (p1 == mx) cand = ln + 64;
        int imin = wmin_all_i(cand);
        if (imin == ln) p0 = -1.f;
        else if (imin == ln+64) p1 = -1.f;
        vals[ts]=mx; idxs[ts]=imin; tw += mx;
      }
      if (ln == 0){
        #pragma unroll
        for (int ts=0;ts<8;ts++){
          selw[ts] = vals[ts]/tw*pes[idxs[ts]];
          seli[ts] = idxs[ts];
        }
      }
    }
  }
}

// ---------------- K5: dense down-proj + MoE gate/up --------------------------
__global__ __launch_bounds__(256) void k_ddown_moegu(const float* __restrict__ Wd,
    const float* __restrict__ act, float* __restrict__ dense,
    const float* __restrict__ pWg, const float* __restrict__ pWu,
    const float* __restrict__ pre2, const int* __restrict__ seli,
    float* __restrict__ hh){
  int lane = threadIdx.x & 63;
  int wv = threadIdx.x >> 6;
  if (blockIdx.x < 704){
    int row = blockIdx.x*4 + wv;
    const float4* wr = (const float4*)(Wd + (size_t)row*D_DENSE);
    const float4* xv = (const float4*)act;
    float acc = 0.f;
    for (int i=lane;i<528;i+=64) acc += dot4(wr[i], xv[i]);
    acc = wsum(acc);
    if (lane==0) dense[row]=acc;
  } else {
    int gidx = (blockIdx.x-704)*4 + wv;
    int sl = gidx / D_FFN;
    int f = gidx - sl*D_FFN;
    int e = seli[sl];
    int p = e >> 4, g = e & 15;
    size_t ro = ((size_t)p*(16*D_FFN) + (size_t)g*D_FFN + f)*D_MODEL;
    const float4* g4 = (const float4*)(pWg + ro);
    const float4* u4 = (const float4*)(pWu + ro);
    const float4* xv = (const float4*)pre2;
    float ag=0.f, au=0.f;
    for (int i=lane;i<DM4;i+=64){
      float4 b=xv[i];
      ag += dot4(g4[i], b);
      au += dot4(u4[i], b);
    }
    ag = wsum(ag); au = wsum(au);
    if (lane==0) hh[sl*D_FFN + f] = gelu_tanh(ag)*au;
  }
}

// ---------------- K6: MoE down-proj + last-block final combine ---------------
__global__ __launch_bounds__(256) void k_moedown_final(const float* __restrict__ Wd,
    const float* __restrict__ hh, const int* __restrict__ seli,
    float* __restrict__ pere,
    const float* __restrict__ selw, const float* __restrict__ dense,
    const float* __restrict__ x1, const float* __restrict__ w2,
    const float* __restrict__ w1, const float* __restrict__ wf,
    const float* __restrict__ lsc, float* __restrict__ out, int* __restrict__ cnt){
  __shared__ float sm[8];
  int t = threadIdx.x;
  int gidx = blockIdx.x*4 + (t>>6);
  int lane = t & 63;
  int sl = gidx / D_MODEL;
  int d = gidx - sl*D_MODEL;
  int e = seli[sl];
  int p = e >> 4, g = e & 15;
  const float4* wr = (const float4*)(Wd + ((size_t)p*(16*D_MODEL) + (size_t)g*D_MODEL + d)*D_FFN);
  const float4* xv = (const float4*)(hh + sl*D_FFN);
  float acc=0.f;
  for (int i=lane;i<DF4;i+=64) acc += dot4(wr[i], xv[i]);
  acc = wsum(acc);
  if (lane==0) pere[sl*D_MODEL + d] = acc;

  __threadfence();
  __syncthreads();
  __shared__ int lastf;
  if (t==0) lastf = (atomicAdd(&cnt[18],1) == 5631);
  __syncthreads();
  if (lastf){
    __threadfence();
    float mo[11], dn[11]; float ssm_=0.f, ssd=0.f;
    #pragma unroll
    for (int i=0;i<11;i++){
      int idx=t+256*i;
      float mv=0.f;
      #pragma unroll
      for (int s=0;s<TOPK;s++) mv = fmaf(selw[s], pere[s*D_MODEL+idx], mv);
      mo[i]=mv; ssm_ += mv*mv;
      dn[i]=dense[idx]; ssd += dn[i]*dn[i];
    }
    ssm_ = block_sum(ssm_, sm);
    ssd = block_sum(ssd, sm);
    float rm = rsqrtf(ssm_/(float)D_MODEL + EPS);
    float rd = rsqrtf(ssd/(float)D_MODEL + EPS);
    float tv[11]; float sst=0.f;
    #pragma unroll
    for (int i=0;i<11;i++){
      int idx=t+256*i;
      float h2 = mo[i]*rm*(1.f+w2[idx]);
      float h1 = dn[i]*rd*(1.f+w1[idx]);
      tv[i]=h1+h2; sst += tv[i]*tv[i];
    }
    sst = block_sum(sst, sm);
    float rt = rsqrtf(sst/(float)D_MODEL + EPS);
    float l = lsc[0];
    #pragma unroll
    for (int i=0;i<11;i++){
      int idx=t+256*i;
      out[idx] = (x1[idx] + tv[i]*rt*(1.f+wf[idx]))*l;
    }
  }
}

extern "C" void kernel_launch(void* const* d_in, const int* in_sizes, int n_in,
                              void* d_out, int out_size, void* d_ws, size_t ws_size,
                              hipStream_t stream){
  const float* x        = (const float*)d_in[0];
  const float* cs       = (const float*)d_in[1];
  const float* sn       = (const float*)d_in[2];
  const float* kc       = (const float*)d_in[3];
  const float* vc       = (const float*)d_in[4];
  const float* mask     = (const float*)d_in[5];
  const float* wm       = (const float*)d_in[6];
  const float* in_ln    = (const float*)d_in[7];
  const float* post_attn= (const float*)d_in[8];
  const float* pre_ffn  = (const float*)d_in[9];
  const float* post_ffn1= (const float*)d_in[10];
  const float* pre_ffn2 = (const float*)d_in[11];
  const float* post_ffn2= (const float*)d_in[12];
  const float* post_ffn = (const float*)d_in[13];
  const float* Wq       = (const float*)d_in[14];
  const float* Wk       = (const float*)d_in[15];
  const float* Wv       = (const float*)d_in[16];
  const float* Wo       = (const float*)d_in[17];
  const float* qnw      = (const float*)d_in[18];
  const float* knw      = (const float*)d_in[19];
  const float* dWg      = (const float*)d_in[20];
  const float* dWu      = (const float*)d_in[21];
  const float* dWd      = (const float*)d_in[22];
  const float* rWp      = (const float*)d_in[23];
  const float* rscale   = (const float*)d_in[24];
  const float* rpes     = (const float*)d_in[25];
  const float* pWg      = (const float*)d_in[26];
  const float* pWu      = (const float*)d_in[27];
  const float* pWd      = (const float*)d_in[28];
  const float* lsc      = (const float*)d_in[29];

  float* out = (float*)d_out;
  float* ko  = out + D_MODEL;
  float* vo  = ko + (size_t)NKV*MAX_CTX*DH;

  float* ws   = (float*)d_ws;
  float* qkv  = ws + 0;        // 8192
  float* ctx  = ws + 16384;    // 4096
  float* a    = ws + 20480;    // 2816
  float* x1   = ws + 23296;    // 2816
  float* pre  = ws + 26112;    // 2816
  float* hr   = ws + 28928;    // 2816
  float* pre2 = ws + 31744;    // 2816
  float* act  = ws + 34560;    // 2112
  float* dense= ws + 36672;    // 2816
  float* lg   = ws + 39488;    // 128
  float* selw = ws + 39616;    // 8
  int*   seli = (int*)(ws + 39624); // 8
  float* hh   = ws + 39632;    // 8*704 = 5632
  float* pere = ws + 45264;    // 8*2816 = 22528
  float* part = ws + 67792;    // 16*16*258 = 66048
  int*   cnt  = (int*)(ws + 133840); // 32 ints

  k_qkv           <<<2048, 256, 0, stream>>>(Wq, Wk, Wv, x, in_ln, qkv, cnt);
  k_attn_copy     <<<4352, 256, 0, stream>>>(kc, vc, qkv, qnw, knw, cs, sn, wm, mask,
                                             ko, vo, part, ctx, cnt);
  k_wo_post       <<<704,  256, 0, stream>>>(Wo, ctx, x, post_attn, pre_ffn, rscale,
                                             pre_ffn2, a, x1, pre, hr, pre2, cnt);
  k_dense_router  <<<560,  256, 0, stream>>>(dWg, dWu, pre, rWp, hr, rpes,
                                             act, lg, selw, seli, cnt);
  k_ddown_moegu   <<<2112, 256, 0, stream>>>(dWd, act, dense, pWg, pWu, pre2, seli, hh);
  k_moedown_final <<<5632, 256, 0, stream>>>(pWd, hh, seli, pere, selw, dense, x1,
                                             post_ffn2, post_ffn1, post_ffn, lsc, out, cnt);
}

// Round 4
// 293.824 us; speedup vs baseline: 2.6612x; 2.6612x over previous
//
#include <hip/hip_runtime.h>
#include <hip/hip_bf16.h>
#include <math.h>

#define D_MODEL 2816
#define DM4 704          // D_MODEL/4
#define D_DENSE 2112
#define N_EXPERTS 128
#define D_FFN 704
#define DF4 176          // D_FFN/4
#define TOPK 8
#define H 16
#define DH 256
#define NKV 8
#define MAX_CTX 4096
#define EPS 1e-6f

__device__ __forceinline__ float wsum(float v){
  #pragma unroll
  for(int o=32;o>0;o>>=1) v += __shfl_down(v, o, 64);
  return v;
}
__device__ __forceinline__ float wmax(float v){
  #pragma unroll
  for(int o=32;o>0;o>>=1) v = fmaxf(v, __shfl_down(v, o, 64));
  return v;
}
__device__ __forceinline__ float wsum_all(float v){
  #pragma unroll
  for(int o=32;o>0;o>>=1) v += __shfl_xor(v, o, 64);
  return v;
}
__device__ __forceinline__ float wmax_all(float v){
  #pragma unroll
  for(int o=32;o>0;o>>=1) v = fmaxf(v, __shfl_xor(v, o, 64));
  return v;
}
__device__ __forceinline__ int wmin_all_i(int v){
  #pragma unroll
  for(int o=32;o>0;o>>=1) v = min(v, __shfl_xor(v, o, 64));
  return v;
}
__device__ __forceinline__ float block_sum(float v, float* sm){
  int lane = threadIdx.x & 63, w = threadIdx.x >> 6;
  int nw = blockDim.x >> 6;
  v = wsum(v);
  __syncthreads();
  if (lane == 0) sm[w] = v;
  __syncthreads();
  float t = 0.f;
  for (int i = 0; i < nw; i++) t += sm[i];
  return t;
}
__device__ __forceinline__ float gelu_tanh(float x){
  float x3 = x*x*x;
  return 0.5f*x*(1.f + tanhf(0.7978845608028654f*(x + 0.044715f*x3)));
}
__device__ __forceinline__ float dot4(float4 a, float4 b){
  return fmaf(a.x,b.x, fmaf(a.y,b.y, fmaf(a.z,b.z, a.w*b.w)));
}
// top-8 indices of lg[128] by value, first-occurrence tie-break (monotone wrt softmax).
// Must be called by wave 0 (t<64); writes seli_lds[8].
__device__ __forceinline__ void topk_idx_wave(const float* __restrict__ lg,
    int t, int* seli_lds){
  float l0 = lg[t], l1 = lg[t+64];
  int idxs[8];
  #pragma unroll
  for (int ts=0;ts<8;ts++){
    float mx = wmax_all(fmaxf(l0,l1));
    int cand = 0x7fffffff;
    if (l0 == mx) cand = t;
    else if (l1 == mx) cand = t + 64;
    int imin = wmin_all_i(cand);
    if (imin == t) l0 = -3.0e38f;
    else if (imin == t+64) l1 = -3.0e38f;
    idxs[ts]=imin;
  }
  if (t == 0){
    #pragma unroll
    for (int ts=0;ts<8;ts++) seli_lds[ts]=idxs[ts];
  }
}

// ---------------- K1: rmsnorm(x) + fused q/k/v GEMV -------------------------
__global__ __launch_bounds__(256) void k_qkv(const float* __restrict__ Wq,
    const float* __restrict__ Wk, const float* __restrict__ Wv,
    const float* __restrict__ x, const float* __restrict__ lw,
    float* __restrict__ out){
  __shared__ float sh[D_MODEL];
  __shared__ float sm[8];
  int t = threadIdx.x;
  float xv[11]; float ss = 0.f;
  #pragma unroll
  for (int i=0;i<11;i++){ xv[i] = x[t + 256*i]; ss += xv[i]*xv[i]; }
  ss = block_sum(ss, sm);
  float r = rsqrtf(ss/(float)D_MODEL + EPS);
  #pragma unroll
  for (int i=0;i<11;i++){ int idx=t+256*i; sh[idx] = xv[i]*r*(1.f+lw[idx]); }
  __syncthreads();

  int row = blockIdx.x*4 + (t>>6);
  int lane = t & 63;
  const float* W; int rr;
  if (row < 4096){ W=Wq; rr=row; }
  else if (row < 6144){ W=Wk; rr=row-4096; }
  else { W=Wv; rr=row-6144; }
  const float4* wr = (const float4*)(W + (size_t)rr*D_MODEL);
  const float4* hv = (const float4*)sh;
  float acc=0.f;
  for (int i=lane;i<DM4;i+=64) acc += dot4(wr[i], hv[i]);
  acc = wsum(acc);
  if (lane==0) out[row]=acc;
}

// ---------------- K2: attn partials (blocks 0..255, self-normed q/k/v) +
//                      KV copy (blocks 256..4351, self-normed). NO fences. ---
__global__ __launch_bounds__(256) void k_kvattn(
    const float* __restrict__ kc, const float* __restrict__ vc,
    const float* __restrict__ qkv,
    const float* __restrict__ qw, const float* __restrict__ kw,
    const float* __restrict__ cs, const float* __restrict__ sn,
    const float* __restrict__ wm, const float* __restrict__ mask,
    float* __restrict__ ko, float* __restrict__ vo,
    float* __restrict__ part){
  __shared__ float sm[8];
  int t = threadIdx.x;

  if (blockIdx.x >= 256){
    // ---- KV copy path: self-norm one head row, then stream the cache ----
    __shared__ float nrm[DH];
    int b = blockIdx.x - 256;
    int tensor = b >> 11;            // 0=k, 1=v
    int head = (b >> 8) & 7;
    int blk = b & 255;
    const float* src = qkv + (tensor ? 6144 : 4096) + head*DH;
    float v = src[t];
    float ssq = block_sum(v*v, sm);
    float r = rsqrtf(ssq/(float)DH + EPS);
    float base_ = v*r*(tensor==0 ? (1.f+kw[t]) : 1.f);
    nrm[t] = base_;
    __syncthreads();
    float nv = base_;
    if (tensor == 0){
      float rot = (t<128) ? -nrm[t+128] : nrm[t-128];
      nv = base_*cs[t] + rot*sn[t];
    }
    __syncthreads();
    nrm[t] = nv;
    __syncthreads();
    const float4* cache = (const float4*)(tensor ? vc : kc);
    float4* outp = (float4*)(tensor ? vo : ko);
    const float4* a4 = (const float4*)nrm;
    size_t hb = (size_t)head * (MAX_CTX*(DH/4));
    int lbase = blk*1024;
    #pragma unroll
    for (int q=0;q<4;q++){
      int jl = lbase + q*256 + t;
      int pos = jl >> 6;
      int d4 = jl & 63;
      float m = wm[pos];
      float4 c = cache[hb + jl];
      float4 a = a4[d4];
      c.x = fmaf(a.x,m,c.x); c.y = fmaf(a.y,m,c.y);
      c.z = fmaf(a.z,m,c.z); c.w = fmaf(a.w,m,c.w);
      outp[hb + jl] = c;
    }
    return;
  }

  // ---- attention partial path (self-normed q/k/v) ----
  __shared__ float qrow[DH], krow[DH], vrow[DH], sc[256], sw[256];
  int head = blockIdx.x >> 4, chunk = blockIdx.x & 15;
  int kvh = head >> 1;                       // rep = H/NKV = 2
  int lane = t & 63, wv = t >> 6;

  {  // q norm + rope
    float v = qkv[head*DH + t];
    float ssq = block_sum(v*v, sm);
    float r = rsqrtf(ssq/(float)DH + EPS);
    float b_ = v*r*(1.f+qw[t]);
    qrow[t]=b_;
    __syncthreads();
    float rot = (t<128) ? -qrow[t+128] : qrow[t-128];
    float nv = b_*cs[t] + rot*sn[t];
    __syncthreads();
    qrow[t]=nv;
  }
  {  // k norm + rope
    float v = qkv[4096 + kvh*DH + t];
    float ssq = block_sum(v*v, sm);
    float r = rsqrtf(ssq/(float)DH + EPS);
    float b_ = v*r*(1.f+kw[t]);
    krow[t]=b_;
    __syncthreads();
    float rot = (t<128) ? -krow[t+128] : krow[t-128];
    float nv = b_*cs[t] + rot*sn[t];
    __syncthreads();
    krow[t]=nv;
  }
  {  // v norm (plain)
    float v = qkv[6144 + kvh*DH + t];
    float ssq = block_sum(v*v, sm);
    vrow[t] = v*rsqrtf(ssq/(float)DH + EPS);
  }
  __syncthreads();

  int base = chunk*256;
  float mk_t = mask[base + t];
  float live = block_sum((mk_t > -1e8f) ? 1.f : 0.f, sm);
  float* p = part + (size_t)(head*16+chunk)*258;
  if (live == 0.f){
    if (t == 0){ p[0] = -3.0e38f; p[1] = 0.f; }
    return;
  }
  float4 q  = ((const float4*)qrow)[lane];
  float4 kp = ((const float4*)krow)[lane];
  float vp  = vrow[t];
  const float* K = kc + (size_t)kvh*MAX_CTX*DH;
  const float* V = vc + (size_t)kvh*MAX_CTX*DH;
  for (int i=0;i<64;i++){
    int pp = wv*64 + i;
    int pos = base + pp;
    float mk = mask[pos];
    float s = -3.0e38f;
    if (mk > -1e8f){                          // wave-uniform
      float m = wm[pos];
      float4 kv = ((const float4*)(K + (size_t)pos*DH))[lane];
      kv.x = fmaf(kp.x, m, kv.x); kv.y = fmaf(kp.y, m, kv.y);
      kv.z = fmaf(kp.z, m, kv.z); kv.w = fmaf(kp.w, m, kv.w);
      float d = wsum(dot4(q, kv));
      s = d + mk;
    }
    if (lane==0) sc[pp] = s;
  }
  __syncthreads();
  float sv = sc[t];
  float mx = wmax(sv);
  __syncthreads();
  if (lane==0) sm[wv]=mx;
  __syncthreads();
  mx = fmaxf(fmaxf(sm[0],sm[1]),fmaxf(sm[2],sm[3]));
  float w = (sv > -1e30f) ? __expf(sv - mx) : 0.f;
  sw[t] = w;
  float ssum = block_sum(w, sm);
  float acc = 0.f;
  for (int i=0;i<256;i++){
    float wi = sw[i];
    if (wi != 0.f){
      float v = fmaf(vp, wm[base+i], V[(size_t)(base+i)*DH + t]);
      acc = fmaf(wi, v, acc);
    }
  }
  if (t==0){ p[0]=mx; p[1]=ssum; }
  p[2+t]=acc;
}

// ---------------- K3: Wo GEMV, each block redundantly combines partials -----
__global__ __launch_bounds__(256) void k_wo(const float* __restrict__ part,
    const float* __restrict__ Wo, float* __restrict__ a){
  __shared__ float sctx[H*DH];   // 16 KB
  int t = threadIdx.x;
  #pragma unroll
  for (int h=0;h<16;h++){
    float M = -3.0e38f;
    for (int c=0;c<16;c++) M = fmaxf(M, part[(size_t)(h*16+c)*258]);
    float tot = 0.f, acc = 0.f;
    for (int c=0;c<16;c++){
      const float* pc = part + (size_t)(h*16+c)*258;
      float mc=pc[0], scv=pc[1];
      if (scv > 0.f){
        float f = __expf(mc - M);
        tot = fmaf(scv, f, tot);
        acc = fmaf(f, pc[2+t], acc);
      }
    }
    sctx[h*DH + t] = acc / tot;
  }
  __syncthreads();
  int row = blockIdx.x*4 + (t>>6);
  int lane = t & 63;
  const float4* wr = (const float4*)(Wo + (size_t)row*(H*DH));
  const float4* xv = (const float4*)sctx;
  float acc = 0.f;
  for (int i=lane;i<H*DH/4;i+=64) acc += dot4(wr[i], xv[i]);
  acc = wsum(acc);
  if (lane==0) a[row]=acc;
}

// ---------------- K4: dense g/u + router logits; every block recomputes
//                      postattn from (a, x); block 0 stores x1/pre2 ----------
__global__ __launch_bounds__(256) void k_dense_router(
    const float* __restrict__ a, const float* __restrict__ x,
    const float* __restrict__ wpost, const float* __restrict__ wpre,
    const float* __restrict__ rscale, const float* __restrict__ wpre2,
    const float* __restrict__ Wg, const float* __restrict__ Wu,
    const float* __restrict__ Wp,
    float* __restrict__ act, float* __restrict__ lg,
    float* __restrict__ x1, float* __restrict__ pre2g){
  __shared__ float sh[D_MODEL];
  __shared__ float sm[8];
  int t = threadIdx.x;
  bool isdense = (blockIdx.x < 528);
  float av[11]; float ss=0.f;
  #pragma unroll
  for (int i=0;i<11;i++){ av[i]=a[t+256*i]; ss += av[i]*av[i]; }
  ss = block_sum(ss, sm);
  float ra = rsqrtf(ss/(float)D_MODEL + EPS);
  float xv[11]; float ss2=0.f;
  #pragma unroll
  for (int i=0;i<11;i++){
    int idx=t+256*i;
    xv[i] = x[idx] + av[i]*ra*(1.f+wpost[idx]);
    ss2 += xv[i]*xv[i];
  }
  ss2 = block_sum(ss2, sm);
  float r1 = rsqrtf(ss2/(float)D_MODEL + EPS);
  const float invsq = rsqrtf((float)D_MODEL);
  #pragma unroll
  for (int i=0;i<11;i++){
    int idx=t+256*i;
    float n = xv[i]*r1;
    sh[idx] = isdense ? n*(1.f+wpre[idx]) : n*rscale[idx]*invsq;
    if (blockIdx.x == 0){
      x1[idx]   = xv[i];
      pre2g[idx]= n*(1.f+wpre2[idx]);
    }
  }
  __syncthreads();

  int lane = t & 63, wv = t >> 6;
  const float4* xv4 = (const float4*)sh;
  if (isdense){
    int row = blockIdx.x*4 + wv;
    const float4* g4 = (const float4*)(Wg + (size_t)row*D_MODEL);
    const float4* u4 = (const float4*)(Wu + (size_t)row*D_MODEL);
    float ag=0.f, au=0.f;
    for (int i=lane;i<DM4;i+=64){
      float4 b = xv4[i];
      ag += dot4(g4[i], b);
      au += dot4(u4[i], b);
    }
    ag = wsum(ag); au = wsum(au);
    if (lane==0) act[row] = gelu_tanh(ag)*au;
  } else {
    int row = (blockIdx.x-528)*4 + wv;       // 0..127
    const float4* wr = (const float4*)(Wp + (size_t)row*D_MODEL);
    float acc = 0.f;
    for (int i=lane;i<DM4;i+=64) acc += dot4(wr[i], xv4[i]);
    acc = wsum(acc);
    if (lane==0) lg[row]=acc;
  }
}

// ---------------- K5: dense down (0..703) + MoE g/u (704..2111, topk prologue)
__global__ __launch_bounds__(256) void k_ddown_moegu(const float* __restrict__ Wd,
    const float* __restrict__ act, float* __restrict__ dense,
    const float* __restrict__ pWg, const float* __restrict__ pWu,
    const float* __restrict__ pre2, const float* __restrict__ lg,
    float* __restrict__ hh){
  int t = threadIdx.x;
  int lane = t & 63, wv = t >> 6;
  if (blockIdx.x < 704){
    int row = blockIdx.x*4 + wv;
    const float4* wr = (const float4*)(Wd + (size_t)row*D_DENSE);
    const float4* xv = (const float4*)act;
    float acc = 0.f;
    for (int i=lane;i<528;i+=64) acc += dot4(wr[i], xv[i]);
    acc = wsum(acc);
    if (lane==0) dense[row]=acc;
    return;
  }
  __shared__ int sseli[8];
  if (t < 64) topk_idx_wave(lg, t, sseli);
  __syncthreads();
  int gidx = (blockIdx.x-704)*4 + wv;
  int sl = gidx / D_FFN;
  int f = gidx - sl*D_FFN;
  int e = sseli[sl];
  int p = e >> 4, g = e & 15;
  size_t ro = ((size_t)p*(16*D_FFN) + (size_t)g*D_FFN + f)*D_MODEL;
  const float4* g4 = (const float4*)(pWg + ro);
  const float4* u4 = (const float4*)(pWu + ro);
  const float4* xv = (const float4*)pre2;
  float ag=0.f, au=0.f;
  for (int i=lane;i<DM4;i+=64){
    float4 b=xv[i];
    ag += dot4(g4[i], b);
    au += dot4(u4[i], b);
  }
  ag = wsum(ag); au = wsum(au);
  if (lane==0) hh[sl*D_FFN + f] = gelu_tanh(ag)*au;
}

// ---------------- K6: MoE down-proj (topk prologue) -------------------------
__global__ __launch_bounds__(256) void k_moedown(const float* __restrict__ Wd,
    const float* __restrict__ hh, const float* __restrict__ lg,
    float* __restrict__ pere){
  __shared__ int sseli[8];
  int t = threadIdx.x;
  if (t < 64) topk_idx_wave(lg, t, sseli);
  __syncthreads();
  int gidx = blockIdx.x*4 + (t>>6);
  int lane = t & 63;
  int sl = gidx / D_MODEL;
  int d = gidx - sl*D_MODEL;
  int e = sseli[sl];
  int p = e >> 4, g = e & 15;
  const float4* wr = (const float4*)(Wd + ((size_t)p*(16*D_MODEL) + (size_t)g*D_MODEL + d)*D_FFN);
  const float4* xv = (const float4*)(hh + sl*D_FFN);
  float acc=0.f;
  for (int i=lane;i<DF4;i+=64) acc += dot4(wr[i], xv[i]);
  acc = wsum(acc);
  if (lane==0) pere[sl*D_MODEL + d] = acc;
}

// ---------------- K7: final combine (1 block; recomputes selw from lg) ------
__global__ __launch_bounds__(256) void k_final(const float* __restrict__ pere,
    const float* __restrict__ lg, const float* __restrict__ pes,
    const float* __restrict__ dense, const float* __restrict__ x1,
    const float* __restrict__ w2, const float* __restrict__ w1,
    const float* __restrict__ wf, const float* __restrict__ lsc,
    float* __restrict__ out){
  __shared__ float sm[8];
  __shared__ float sselw[8];
  int t = threadIdx.x;
  if (t < 64){
    float l0 = lg[t], l1 = lg[t+64];
    float m = wmax_all(fmaxf(l0,l1));
    float e0 = __expf(l0-m), e1 = __expf(l1-m);
    float s = wsum_all(e0+e1);
    float p0 = e0/s, p1 = e1/s;
    float vals[8]; int idxs[8]; float tw=0.f;
    #pragma unroll
    for (int ts=0;ts<8;ts++){
      float mx = wmax_all(fmaxf(p0,p1));
      int cand = 0x7fffffff;
      if (p0 == mx) cand = t;
      else if (p1 == mx) cand = t + 64;
      int imin = wmin_all_i(cand);
      if (imin == t) p0 = -1.f;
      else if (imin == t+64) p1 = -1.f;
      vals[ts]=mx; idxs[ts]=imin; tw += mx;
    }
    if (t == 0){
      #pragma unroll
      for (int ts=0;ts<8;ts++) sselw[ts] = vals[ts]/tw*pes[idxs[ts]];
    }
  }
  __syncthreads();
  float mo[11], dn[11]; float ssm_=0.f, ssd=0.f;
  #pragma unroll
  for (int i=0;i<11;i++){
    int idx=t+256*i;
    float mv=0.f;
    #pragma unroll
    for (int s=0;s<TOPK;s++) mv = fmaf(sselw[s], pere[s*D_MODEL+idx], mv);
    mo[i]=mv; ssm_ += mv*mv;
    dn[i]=dense[idx]; ssd += dn[i]*dn[i];
  }
  ssm_ = block_sum(ssm_, sm);
  ssd = block_sum(ssd, sm);
  float rm = rsqrtf(ssm_/(float)D_MODEL + EPS);
  float rd = rsqrtf(ssd/(float)D_MODEL + EPS);
  float tv[11]; float sst=0.f;
  #pragma unroll
  for (int i=0;i<11;i++){
    int idx=t+256*i;
    float h2 = mo[i]*rm*(1.f+w2[idx]);
    float h1 = dn[i]*rd*(1.f+w1[idx]);
    tv[i]=h1+h2; sst += tv[i]*tv[i];
  }
  sst = block_sum(sst, sm);
  float rt = rsqrtf(sst/(float)D_MODEL + EPS);
  float l = lsc[0];
  #pragma unroll
  for (int i=0;i<11;i++){
    int idx=t+256*i;
    out[idx] = (x1[idx] + tv[i]*rt*(1.f+wf[idx]))*l;
  }
}

extern "C" void kernel_launch(void* const* d_in, const int* in_sizes, int n_in,
                              void* d_out, int out_size, void* d_ws, size_t ws_size,
                              hipStream_t stream){
  const float* x        = (const float*)d_in[0];
  const float* cs       = (const float*)d_in[1];
  const float* sn       = (const float*)d_in[2];
  const float* kc       = (const float*)d_in[3];
  const float* vc       = (const float*)d_in[4];
  const float* mask     = (const float*)d_in[5];
  const float* wm       = (const float*)d_in[6];
  const float* in_ln    = (const float*)d_in[7];
  const float* post_attn= (const float*)d_in[8];
  const float* pre_ffn  = (const float*)d_in[9];
  const float* post_ffn1= (const float*)d_in[10];
  const float* pre_ffn2 = (const float*)d_in[11];
  const float* post_ffn2= (const float*)d_in[12];
  const float* post_ffn = (const float*)d_in[13];
  const float* Wq       = (const float*)d_in[14];
  const float* Wk       = (const float*)d_in[15];
  const float* Wv       = (const float*)d_in[16];
  const float* Wo       = (const float*)d_in[17];
  const float* qnw      = (const float*)d_in[18];
  const float* knw      = (const float*)d_in[19];
  const float* dWg      = (const float*)d_in[20];
  const float* dWu      = (const float*)d_in[21];
  const float* dWd      = (const float*)d_in[22];
  const float* rWp      = (const float*)d_in[23];
  const float* rscale   = (const float*)d_in[24];
  const float* rpes     = (const float*)d_in[25];
  const float* pWg      = (const float*)d_in[26];
  const float* pWu      = (const float*)d_in[27];
  const float* pWd      = (const float*)d_in[28];
  const float* lsc      = (const float*)d_in[29];

  float* out = (float*)d_out;
  float* ko  = out + D_MODEL;
  float* vo  = ko + (size_t)NKV*MAX_CTX*DH;

  float* ws   = (float*)d_ws;
  float* qkv  = ws + 0;        // 8192
  float* a    = ws + 8192;     // 2816
  float* x1   = ws + 11008;    // 2816
  float* pre2 = ws + 13824;    // 2816
  float* act  = ws + 16640;    // 2112
  float* dense= ws + 18752;    // 2816
  float* lg   = ws + 21568;    // 128
  float* hh   = ws + 21696;    // 8*704 = 5632
  float* pere = ws + 27328;    // 8*2816 = 22528
  float* part = ws + 49856;    // 16*16*258 = 66048

  k_qkv          <<<2048, 256, 0, stream>>>(Wq, Wk, Wv, x, in_ln, qkv);
  k_kvattn       <<<4352, 256, 0, stream>>>(kc, vc, qkv, qnw, knw, cs, sn, wm, mask,
                                            ko, vo, part);
  k_wo           <<<704,  256, 0, stream>>>(part, Wo, a);
  k_dense_router <<<560,  256, 0, stream>>>(a, x, post_attn, pre_ffn, rscale, pre_ffn2,
                                            dWg, dWu, rWp, act, lg, x1, pre2);
  k_ddown_moegu  <<<2112, 256, 0, stream>>>(dWd, act, dense, pWg, pWu, pre2, lg, hh);
  k_moedown      <<<5632, 256, 0, stream>>>(pWd, hh, lg, pere);
  k_final        <<<1,    256, 0, stream>>>(pere, lg, rpes, dense, x1,
                                            post_ffn2, post_ffn1, post_ffn, lsc, out);
}

// Round 5
// 266.262 us; speedup vs baseline: 2.9367x; 1.1035x over previous
//
#include <hip/hip_runtime.h>
#include <hip/hip_bf16.h>
#include <math.h>

#define D_MODEL 2816
#define DM4 704          // D_MODEL/4
#define D_DENSE 2112
#define N_EXPERTS 128
#define D_FFN 704
#define DF4 176          // D_FFN/4
#define TOPK 8
#define H 16
#define DH 256
#define NKV 8
#define MAX_CTX 4096
#define EPS 1e-6f

__device__ __forceinline__ float wsum(float v){
  #pragma unroll
  for(int o=32;o>0;o>>=1) v += __shfl_down(v, o, 64);
  return v;
}
__device__ __forceinline__ float wmax(float v){
  #pragma unroll
  for(int o=32;o>0;o>>=1) v = fmaxf(v, __shfl_down(v, o, 64));
  return v;
}
__device__ __forceinline__ float wsum_all(float v){
  #pragma unroll
  for(int o=32;o>0;o>>=1) v += __shfl_xor(v, o, 64);
  return v;
}
__device__ __forceinline__ float wmax_all(float v){
  #pragma unroll
  for(int o=32;o>0;o>>=1) v = fmaxf(v, __shfl_xor(v, o, 64));
  return v;
}
__device__ __forceinline__ int wmin_all_i(int v){
  #pragma unroll
  for(int o=32;o>0;o>>=1) v = min(v, __shfl_xor(v, o, 64));
  return v;
}
__device__ __forceinline__ float block_sum(float v, float* sm){
  int lane = threadIdx.x & 63, w = threadIdx.x >> 6;
  int nw = blockDim.x >> 6;
  v = wsum(v);
  __syncthreads();
  if (lane == 0) sm[w] = v;
  __syncthreads();
  float t = 0.f;
  for (int i = 0; i < nw; i++) t += sm[i];
  return t;
}
__device__ __forceinline__ float gelu_tanh(float x){
  float x3 = x*x*x;
  return 0.5f*x*(1.f + tanhf(0.7978845608028654f*(x + 0.044715f*x3)));
}
__device__ __forceinline__ float dot4(float4 a, float4 b){
  return fmaf(a.x,b.x, fmaf(a.y,b.y, fmaf(a.z,b.z, a.w*b.w)));
}
// top-8 indices of lg[128] by value, first-occurrence tie-break (monotone wrt
// softmax). Deterministic: same lg -> same result in every block.
// Must be called by wave 0 (t<64); writes seli_lds[8].
__device__ __forceinline__ void topk_idx_wave(const float* __restrict__ lg,
    int t, int* seli_lds){
  float l0 = lg[t], l1 = lg[t+64];
  int idxs[8];
  #pragma unroll
  for (int ts=0;ts<8;ts++){
    float mx = wmax_all(fmaxf(l0,l1));
    int cand = 0x7fffffff;
    if (l0 == mx) cand = t;
    else if (l1 == mx) cand = t + 64;
    int imin = wmin_all_i(cand);
    if (imin == t) l0 = -3.0e38f;
    else if (imin == t+64) l1 = -3.0e38f;
    idxs[ts]=imin;
  }
  if (t == 0){
    #pragma unroll
    for (int ts=0;ts<8;ts++) seli_lds[ts]=idxs[ts];
  }
}

// ---------------- K1: rmsnorm(x) + fused q/k/v GEMV -------------------------
__global__ __launch_bounds__(256) void k_qkv(const float* __restrict__ Wq,
    const float* __restrict__ Wk, const float* __restrict__ Wv,
    const float* __restrict__ x, const float* __restrict__ lw,
    float* __restrict__ out){
  __shared__ float sh[D_MODEL];
  __shared__ float sm[8];
  int t = threadIdx.x;
  float xv[11]; float ss = 0.f;
  #pragma unroll
  for (int i=0;i<11;i++){ xv[i] = x[t + 256*i]; ss += xv[i]*xv[i]; }
  ss = block_sum(ss, sm);
  float r = rsqrtf(ss/(float)D_MODEL + EPS);
  #pragma unroll
  for (int i=0;i<11;i++){ int idx=t+256*i; sh[idx] = xv[i]*r*(1.f+lw[idx]); }
  __syncthreads();

  int row = blockIdx.x*4 + (t>>6);
  int lane = t & 63;
  const float* W; int rr;
  if (row < 4096){ W=Wq; rr=row; }
  else if (row < 6144){ W=Wk; rr=row-4096; }
  else { W=Wv; rr=row-6144; }
  const float4* wr = (const float4*)(W + (size_t)rr*D_MODEL);
  const float4* hv = (const float4*)sh;
  float acc=0.f;
  for (int i=lane;i<DM4;i+=64) acc += dot4(wr[i], hv[i]);
  acc = wsum(acc);
  if (lane==0) out[row]=acc;
}

// ---------------- K2: attn partials (blocks 0..255, self-normed q/k/v) +
//                      KV copy (blocks 256..4351, self-normed). No fences. ---
__global__ __launch_bounds__(256) void k_kvattn(
    const float* __restrict__ kc, const float* __restrict__ vc,
    const float* __restrict__ qkv,
    const float* __restrict__ qw, const float* __restrict__ kw,
    const float* __restrict__ cs, const float* __restrict__ sn,
    const float* __restrict__ wm, const float* __restrict__ mask,
    float* __restrict__ ko, float* __restrict__ vo,
    float* __restrict__ part){
  __shared__ float sm[8];
  int t = threadIdx.x;

  if (blockIdx.x >= 256){
    // ---- KV copy path: self-norm one head row, then stream the cache ----
    __shared__ float nrm[DH];
    int b = blockIdx.x - 256;
    int tensor = b >> 11;            // 0=k, 1=v
    int head = (b >> 8) & 7;
    int blk = b & 255;
    const float* src = qkv + (tensor ? 6144 : 4096) + head*DH;
    float v = src[t];
    float ssq = block_sum(v*v, sm);
    float r = rsqrtf(ssq/(float)DH + EPS);
    float base_ = v*r*(tensor==0 ? (1.f+kw[t]) : 1.f);
    nrm[t] = base_;
    __syncthreads();
    float nv = base_;
    if (tensor == 0){
      float rot = (t<128) ? -nrm[t+128] : nrm[t-128];
      nv = base_*cs[t] + rot*sn[t];
    }
    __syncthreads();
    nrm[t] = nv;
    __syncthreads();
    const float4* cache = (const float4*)(tensor ? vc : kc);
    float4* outp = (float4*)(tensor ? vo : ko);
    const float4* a4 = (const float4*)nrm;
    size_t hb = (size_t)head * (MAX_CTX*(DH/4));
    int lbase = blk*1024;
    #pragma unroll
    for (int q=0;q<4;q++){
      int jl = lbase + q*256 + t;
      int pos = jl >> 6;
      int d4 = jl & 63;
      float m = wm[pos];
      float4 c = cache[hb + jl];
      float4 a = a4[d4];
      c.x = fmaf(a.x,m,c.x); c.y = fmaf(a.y,m,c.y);
      c.z = fmaf(a.z,m,c.z); c.w = fmaf(a.w,m,c.w);
      outp[hb + jl] = c;
    }
    return;
  }

  // ---- attention partial path (self-normed q/k/v) ----
  __shared__ float qrow[DH], krow[DH], vrow[DH], sc[256], sw[256];
  int head = blockIdx.x >> 4, chunk = blockIdx.x & 15;
  int kvh = head >> 1;                       // rep = H/NKV = 2
  int lane = t & 63, wv = t >> 6;

  {  // q norm + rope
    float v = qkv[head*DH + t];
    float ssq = block_sum(v*v, sm);
    float r = rsqrtf(ssq/(float)DH + EPS);
    float b_ = v*r*(1.f+qw[t]);
    qrow[t]=b_;
    __syncthreads();
    float rot = (t<128) ? -qrow[t+128] : qrow[t-128];
    float nv = b_*cs[t] + rot*sn[t];
    __syncthreads();
    qrow[t]=nv;
  }
  {  // k norm + rope
    float v = qkv[4096 + kvh*DH + t];
    float ssq = block_sum(v*v, sm);
    float r = rsqrtf(ssq/(float)DH + EPS);
    float b_ = v*r*(1.f+kw[t]);
    krow[t]=b_;
    __syncthreads();
    float rot = (t<128) ? -krow[t+128] : krow[t-128];
    float nv = b_*cs[t] + rot*sn[t];
    __syncthreads();
    krow[t]=nv;
  }
  {  // v norm (plain)
    float v = qkv[6144 + kvh*DH + t];
    float ssq = block_sum(v*v, sm);
    vrow[t] = v*rsqrtf(ssq/(float)DH + EPS);
  }
  __syncthreads();

  int base = chunk*256;
  float mk_t = mask[base + t];
  float live = block_sum((mk_t > -1e8f) ? 1.f : 0.f, sm);
  float* p = part + (size_t)(head*16+chunk)*258;
  if (live == 0.f){
    if (t == 0){ p[0] = -3.0e38f; p[1] = 0.f; }
    return;
  }
  float4 q  = ((const float4*)qrow)[lane];
  float4 kp = ((const float4*)krow)[lane];
  float vp  = vrow[t];
  const float* K = kc + (size_t)kvh*MAX_CTX*DH;
  const float* V = vc + (size_t)kvh*MAX_CTX*DH;
  for (int i=0;i<64;i++){
    int pp = wv*64 + i;
    int pos = base + pp;
    float mk = mask[pos];
    float s = -3.0e38f;
    if (mk > -1e8f){                          // wave-uniform
      float m = wm[pos];
      float4 kv = ((const float4*)(K + (size_t)pos*DH))[lane];
      kv.x = fmaf(kp.x, m, kv.x); kv.y = fmaf(kp.y, m, kv.y);
      kv.z = fmaf(kp.z, m, kv.z); kv.w = fmaf(kp.w, m, kv.w);
      float d = wsum(dot4(q, kv));
      s = d + mk;
    }
    if (lane==0) sc[pp] = s;
  }
  __syncthreads();
  float sv = sc[t];
  float mx = wmax(sv);
  __syncthreads();
  if (lane==0) sm[wv]=mx;
  __syncthreads();
  mx = fmaxf(fmaxf(sm[0],sm[1]),fmaxf(sm[2],sm[3]));
  float w = (sv > -1e30f) ? __expf(sv - mx) : 0.f;
  sw[t] = w;
  float ssum = block_sum(w, sm);
  float acc = 0.f;
  for (int i=0;i<256;i++){
    float wi = sw[i];
    if (wi != 0.f){
      float v = fmaf(vp, wm[base+i], V[(size_t)(base+i)*DH + t]);
      acc = fmaf(wi, v, acc);
    }
  }
  if (t==0){ p[0]=mx; p[1]=ssum; }
  p[2+t]=acc;
}

// ---------------- K3: combine partials -> ctx (16 blocks, once) -------------
__global__ __launch_bounds__(256) void k_attn_comb(const float* __restrict__ part,
    float* __restrict__ ctx){
  int head = blockIdx.x, t = threadIdx.x;
  float M = -3.0e38f;
  for (int c=0;c<16;c++) M = fmaxf(M, part[(size_t)(head*16+c)*258]);
  float tot = 0.f, acc = 0.f;
  for (int c=0;c<16;c++){
    const float* p = part + (size_t)(head*16+c)*258;
    float mc=p[0], scv=p[1];
    if (scv > 0.f){
      float f = __expf(mc - M);
      tot = fmaf(scv, f, tot);
      acc = fmaf(f, p[2+t], acc);
    }
  }
  ctx[head*DH + t] = acc / tot;
}

// ---------------- K4: Wo GEMV (plain) ---------------------------------------
__global__ __launch_bounds__(256) void k_wo(const float* __restrict__ Wo,
    const float* __restrict__ ctxv, float* __restrict__ a){
  int t = threadIdx.x;
  int row = blockIdx.x*4 + (t>>6);
  int lane = t & 63;
  const float4* wr = (const float4*)(Wo + (size_t)row*(H*DH));
  const float4* xv = (const float4*)ctxv;
  float acc = 0.f;
  for (int i=lane;i<H*DH/4;i+=64) acc += dot4(wr[i], xv[i]);
  acc = wsum(acc);
  if (lane==0) a[row]=acc;
}

// ---------------- K5: dense g/u + router logits; every block recomputes
//                      postattn from (a, x); block 0 stores x1/pre2 ----------
__global__ __launch_bounds__(256) void k_dense_router(
    const float* __restrict__ a, const float* __restrict__ x,
    const float* __restrict__ wpost, const float* __restrict__ wpre,
    const float* __restrict__ rscale, const float* __restrict__ wpre2,
    const float* __restrict__ Wg, const float* __restrict__ Wu,
    const float* __restrict__ Wp,
    float* __restrict__ act, float* __restrict__ lg,
    float* __restrict__ x1, float* __restrict__ pre2g){
  __shared__ float sh[D_MODEL];
  __shared__ float sm[8];
  int t = threadIdx.x;
  bool isdense = (blockIdx.x < 528);
  float av[11]; float ss=0.f;
  #pragma unroll
  for (int i=0;i<11;i++){ av[i]=a[t+256*i]; ss += av[i]*av[i]; }
  ss = block_sum(ss, sm);
  float ra = rsqrtf(ss/(float)D_MODEL + EPS);
  float xv[11]; float ss2=0.f;
  #pragma unroll
  for (int i=0;i<11;i++){
    int idx=t+256*i;
    xv[i] = x[idx] + av[i]*ra*(1.f+wpost[idx]);
    ss2 += xv[i]*xv[i];
  }
  ss2 = block_sum(ss2, sm);
  float r1 = rsqrtf(ss2/(float)D_MODEL + EPS);
  const float invsq = rsqrtf((float)D_MODEL);
  #pragma unroll
  for (int i=0;i<11;i++){
    int idx=t+256*i;
    float n = xv[i]*r1;
    sh[idx] = isdense ? n*(1.f+wpre[idx]) : n*rscale[idx]*invsq;
    if (blockIdx.x == 0){
      x1[idx]   = xv[i];
      pre2g[idx]= n*(1.f+wpre2[idx]);
    }
  }
  __syncthreads();

  int lane = t & 63, wv = t >> 6;
  const float4* xv4 = (const float4*)sh;
  if (isdense){
    int row = blockIdx.x*4 + wv;
    const float4* g4 = (const float4*)(Wg + (size_t)row*D_MODEL);
    const float4* u4 = (const float4*)(Wu + (size_t)row*D_MODEL);
    float ag=0.f, au=0.f;
    for (int i=lane;i<DM4;i+=64){
      float4 b = xv4[i];
      ag += dot4(g4[i], b);
      au += dot4(u4[i], b);
    }
    ag = wsum(ag); au = wsum(au);
    if (lane==0) act[row] = gelu_tanh(ag)*au;
  } else {
    int row = (blockIdx.x-528)*4 + wv;       // 0..127
    const float4* wr = (const float4*)(Wp + (size_t)row*D_MODEL);
    float acc = 0.f;
    for (int i=lane;i<DM4;i+=64) acc += dot4(wr[i], xv4[i]);
    acc = wsum(acc);
    if (lane==0) lg[row]=acc;
  }
}

// ---------------- K6: dense down (0..703) + MoE g/u (704..2111, topk prologue)
__global__ __launch_bounds__(256) void k_ddown_moegu(const float* __restrict__ Wd,
    const float* __restrict__ act, float* __restrict__ dense,
    const float* __restrict__ pWg, const float* __restrict__ pWu,
    const float* __restrict__ pre2, const float* __restrict__ lg,
    float* __restrict__ hh){
  int t = threadIdx.x;
  int lane = t & 63, wv = t >> 6;
  if (blockIdx.x < 704){
    int row = blockIdx.x*4 + wv;
    const float4* wr = (const float4*)(Wd + (size_t)row*D_DENSE);
    const float4* xv = (const float4*)act;
    float acc = 0.f;
    for (int i=lane;i<528;i+=64) acc += dot4(wr[i], xv[i]);
    acc = wsum(acc);
    if (lane==0) dense[row]=acc;
    return;
  }
  __shared__ int sseli[8];
  if (t < 64) topk_idx_wave(lg, t, sseli);
  __syncthreads();
  int gidx = (blockIdx.x-704)*4 + wv;
  int sl = gidx / D_FFN;
  int f = gidx - sl*D_FFN;
  int e = sseli[sl];
  int p = e >> 4, g = e & 15;
  size_t ro = ((size_t)p*(16*D_FFN) + (size_t)g*D_FFN + f)*D_MODEL;
  const float4* g4 = (const float4*)(pWg + ro);
  const float4* u4 = (const float4*)(pWu + ro);
  const float4* xv = (const float4*)pre2;
  float ag=0.f, au=0.f;
  for (int i=lane;i<DM4;i+=64){
    float4 b=xv[i];
    ag += dot4(g4[i], b);
    au += dot4(u4[i], b);
  }
  ag = wsum(ag); au = wsum(au);
  if (lane==0) hh[sl*D_FFN + f] = gelu_tanh(ag)*au;
}

// ---------------- K7: MoE down-proj (topk prologue) -------------------------
__global__ __launch_bounds__(256) void k_moedown(const float* __restrict__ Wd,
    const float* __restrict__ hh, const float* __restrict__ lg,
    float* __restrict__ pere){
  __shared__ int sseli[8];
  int t = threadIdx.x;
  if (t < 64) topk_idx_wave(lg, t, sseli);
  __syncthreads();
  int gidx = blockIdx.x*4 + (t>>6);
  int lane = t & 63;
  int sl = gidx / D_MODEL;
  int d = gidx - sl*D_MODEL;
  int e = sseli[sl];
  int p = e >> 4, g = e & 15;
  const float4* wr = (const float4*)(Wd + ((size_t)p*(16*D_MODEL) + (size_t)g*D_MODEL + d)*D_FFN);
  const float4* xv = (const float4*)(hh + sl*D_FFN);
  float acc=0.f;
  for (int i=lane;i<DF4;i+=64) acc += dot4(wr[i], xv[i]);
  acc = wsum(acc);
  if (lane==0) pere[sl*D_MODEL + d] = acc;
}

// ---------------- K8: final combine (1 block; recomputes selw from lg) ------
__global__ __launch_bounds__(256) void k_final(const float* __restrict__ pere,
    const float* __restrict__ lg, const float* __restrict__ pes,
    const float* __restrict__ dense, const float* __restrict__ x1,
    const float* __restrict__ w2, const float* __restrict__ w1,
    const float* __restrict__ wf, const float* __restrict__ lsc,
    float* __restrict__ out){
  __shared__ float sm[8];
  __shared__ float sselw[8];
  int t = threadIdx.x;
  if (t < 64){
    float l0 = lg[t], l1 = lg[t+64];
    float m = wmax_all(fmaxf(l0,l1));
    float e0 = __expf(l0-m), e1 = __expf(l1-m);
    float s = wsum_all(e0+e1);
    float p0 = e0/s, p1 = e1/s;
    float vals[8]; int idxs[8]; float tw=0.f;
    #pragma unroll
    for (int ts=0;ts<8;ts++){
      float mx = wmax_all(fmaxf(p0,p1));
      int cand = 0x7fffffff;
      if (p0 == mx) cand = t;
      else if (p1 == mx) cand = t + 64;
      int imin = wmin_all_i(cand);
      if (imin == t) p0 = -1.f;
      else if (imin == t+64) p1 = -1.f;
      vals[ts]=mx; idxs[ts]=imin; tw += mx;
    }
    if (t == 0){
      #pragma unroll
      for (int ts=0;ts<8;ts++) sselw[ts] = vals[ts]/tw*pes[idxs[ts]];
    }
  }
  __syncthreads();
  float mo[11], dn[11]; float ssm_=0.f, ssd=0.f;
  #pragma unroll
  for (int i=0;i<11;i++){
    int idx=t+256*i;
    float mv=0.f;
    #pragma unroll
    for (int s=0;s<TOPK;s++) mv = fmaf(sselw[s], pere[s*D_MODEL+idx], mv);
    mo[i]=mv; ssm_ += mv*mv;
    dn[i]=dense[idx]; ssd += dn[i]*dn[i];
  }
  ssm_ = block_sum(ssm_, sm);
  ssd = block_sum(ssd, sm);
  float rm = rsqrtf(ssm_/(float)D_MODEL + EPS);
  float rd = rsqrtf(ssd/(float)D_MODEL + EPS);
  float tv[11]; float sst=0.f;
  #pragma unroll
  for (int i=0;i<11;i++){
    int idx=t+256*i;
    float h2 = mo[i]*rm*(1.f+w2[idx]);
    float h1 = dn[i]*rd*(1.f+w1[idx]);
    tv[i]=h1+h2; sst += tv[i]*tv[i];
  }
  sst = block_sum(sst, sm);
  float rt = rsqrtf(sst/(float)D_MODEL + EPS);
  float l = lsc[0];
  #pragma unroll
  for (int i=0;i<11;i++){
    int idx=t+256*i;
    out[idx] = (x1[idx] + tv[i]*rt*(1.f+wf[idx]))*l;
  }
}

extern "C" void kernel_launch(void* const* d_in, const int* in_sizes, int n_in,
                              void* d_out, int out_size, void* d_ws, size_t ws_size,
                              hipStream_t stream){
  const float* x        = (const float*)d_in[0];
  const float* cs       = (const float*)d_in[1];
  const float* sn       = (const float*)d_in[2];
  const float* kc       = (const float*)d_in[3];
  const float* vc       = (const float*)d_in[4];
  const float* mask     = (const float*)d_in[5];
  const float* wm       = (const float*)d_in[6];
  const float* in_ln    = (const float*)d_in[7];
  const float* post_attn= (const float*)d_in[8];
  const float* pre_ffn  = (const float*)d_in[9];
  const float* post_ffn1= (const float*)d_in[10];
  const float* pre_ffn2 = (const float*)d_in[11];
  const float* post_ffn2= (const float*)d_in[12];
  const float* post_ffn = (const float*)d_in[13];
  const float* Wq       = (const float*)d_in[14];
  const float* Wk       = (const float*)d_in[15];
  const float* Wv       = (const float*)d_in[16];
  const float* Wo       = (const float*)d_in[17];
  const float* qnw      = (const float*)d_in[18];
  const float* knw      = (const float*)d_in[19];
  const float* dWg      = (const float*)d_in[20];
  const float* dWu      = (const float*)d_in[21];
  const float* dWd      = (const float*)d_in[22];
  const float* rWp      = (const float*)d_in[23];
  const float* rscale   = (const float*)d_in[24];
  const float* rpes     = (const float*)d_in[25];
  const float* pWg      = (const float*)d_in[26];
  const float* pWu      = (const float*)d_in[27];
  const float* pWd      = (const float*)d_in[28];
  const float* lsc      = (const float*)d_in[29];

  float* out = (float*)d_out;
  float* ko  = out + D_MODEL;
  float* vo  = ko + (size_t)NKV*MAX_CTX*DH;

  float* ws   = (float*)d_ws;
  float* qkv  = ws + 0;        // 8192
  float* ctx  = ws + 8192;     // 4096
  float* a    = ws + 12288;    // 2816
  float* x1   = ws + 15104;    // 2816
  float* pre2 = ws + 17920;    // 2816
  float* act  = ws + 20736;    // 2112
  float* dense= ws + 22848;    // 2816
  float* lg   = ws + 25664;    // 128
  float* hh   = ws + 25792;    // 8*704 = 5632
  float* pere = ws + 31424;    // 8*2816 = 22528
  float* part = ws + 53952;    // 16*16*258 = 66048

  k_qkv          <<<2048, 256, 0, stream>>>(Wq, Wk, Wv, x, in_ln, qkv);
  k_kvattn       <<<4352, 256, 0, stream>>>(kc, vc, qkv, qnw, knw, cs, sn, wm, mask,
                                            ko, vo, part);
  k_attn_comb    <<<16,   256, 0, stream>>>(part, ctx);
  k_wo           <<<704,  256, 0, stream>>>(Wo, ctx, a);
  k_dense_router <<<560,  256, 0, stream>>>(a, x, post_attn, pre_ffn, rscale, pre_ffn2,
                                            dWg, dWu, rWp, act, lg, x1, pre2);
  k_ddown_moegu  <<<2112, 256, 0, stream>>>(dWd, act, dense, pWg, pWu, pre2, lg, hh);
  k_moedown      <<<5632, 256, 0, stream>>>(pWd, hh, lg, pere);
  k_final        <<<1,    256, 0, stream>>>(pere, lg, rpes, dense, x1,
                                            post_ffn2, post_ffn1, post_ffn, lsc, out);
}